// Round 2
// baseline (248.627 us; speedup 1.0000x reference)
//
#include <hip/hip_runtime.h>

#define N_NODES 100000
#define N_EDGES 1250000
#define D 64

#define BSHIFT 9
#define BUCKETS 196          // ceil(100000 / 512)
#define CAP 8192             // srtTmp capacity per bucket (mean 6378, +22 sigma)
#define CHUNK 4096           // edges per bucketA block
#define PA_BLOCKS ((N_EDGES + CHUNK - 1) / CHUNK)   // 306
#define LCAP 64              // LDS list capacity per bucket per chunk (mean 21)

typedef long long ll;
typedef unsigned int uint;

// round-to-nearest-even fp32 -> bf16
__device__ __forceinline__ ushort f2bf(float f) {
    uint u = __float_as_uint(f);
    u += 0x7fffu + ((u >> 16) & 1u);
    return (ushort)(u >> 16);
}

// ---------- init: cursor[b] = b*CAP; zero-pad srt tail; offs[N] sentinel ----------
__global__ void init_kernel(int* __restrict__ cursor, int* __restrict__ srt,
                            int* __restrict__ offs) {
    int t = threadIdx.x;
    if (t < BUCKETS) cursor[t] = t * CAP;
    if (t < 8) srt[N_EDGES + t] = 0;
    if (t == 0) offs[N_NODES] = N_EDGES;
}

// ---------- pass A: bin edges into 196 coarse buckets, coalesced flushes ----------
__global__ __launch_bounds__(256) void bucketA_kernel(const int* __restrict__ src,
                                                      const int* __restrict__ dst,
                                                      int* __restrict__ cursor,
                                                      int* __restrict__ tmp) {
    __shared__ int lcnt[BUCKETS];
    __shared__ int list[BUCKETS * LCAP];   // ~50 KB
    int tid = threadIdx.x;
    for (int b = tid; b < BUCKETS; b += 256) lcnt[b] = 0;
    __syncthreads();

    int base = blockIdx.x * CHUNK;
    int nE = min(CHUNK, N_EDGES - base);
    for (int i = tid; i < nE; i += 256) {
        int e = base + i;
        int s = src[e], d = dst[e];
        int b = d >> BSHIFT;
        int p = atomicAdd(&lcnt[b], 1);            // LDS atomic, cheap
        list[b * LCAP + p] = s | ((d & 511) << 17); // src:17b, dstLow:9b
    }
    __syncthreads();

    // one global atomic per (block, bucket); flush run is contiguous
    for (int b = tid; b < BUCKETS; b += 256) {
        int c = lcnt[b];
        if (c > 0) {
            int gb = atomicAdd(&cursor[b], c);
            for (int k = 0; k < c; ++k) tmp[gb + k] = list[b * LCAP + k];
        }
    }
}

// ---------- tiny scan: bucket bases from cursor counts ----------
__global__ void scanSmall_kernel(const int* __restrict__ cursor, int* __restrict__ bbase) {
    __shared__ int s[256];
    int tid = threadIdx.x;
    int x = (tid < BUCKETS) ? (cursor[tid] - tid * CAP) : 0;
    s[tid] = x;
    __syncthreads();
    for (int off = 1; off < 256; off <<= 1) {
        int v = (tid >= off) ? s[tid - off] : 0;
        __syncthreads();
        s[tid] += v;
        __syncthreads();
    }
    if (tid < BUCKETS) bbase[tid] = s[tid] - x;   // exclusive
}

// ---------- pass B: per-bucket local sort -> final srt + offs ----------
__global__ __launch_bounds__(512) void bucketB_kernel(const int* __restrict__ cursor,
                                                      const int* __restrict__ bbase,
                                                      const int* __restrict__ tmp,
                                                      int* __restrict__ srt,
                                                      int* __restrict__ offs) {
    __shared__ int hist[512];
    __shared__ int s[512];
    __shared__ int cur[512];
    int b = blockIdx.x, tid = threadIdx.x;
    int cbase = b * CAP;
    int cnt = cursor[b] - cbase;
    int gbase = bbase[b];

    hist[tid] = 0;
    __syncthreads();
    for (int i = tid; i < cnt; i += 512) {
        int ln = tmp[cbase + i] >> 17;
        atomicAdd(&hist[ln], 1);          // LDS atomic, avg 12.5/node
    }
    __syncthreads();

    // inclusive Hillis-Steele over 512 -> exclusive
    int x = hist[tid];
    s[tid] = x;
    __syncthreads();
    for (int off = 1; off < 512; off <<= 1) {
        int v = (tid >= off) ? s[tid - off] : 0;
        __syncthreads();
        s[tid] += v;
        __syncthreads();
    }
    int excl = s[tid] - x;
    cur[tid] = excl;

    int node0 = b << BSHIFT;
    int nloc = min(512, N_NODES - node0);
    if (tid < nloc) offs[node0 + tid] = gbase + excl;   // coalesced
    __syncthreads();

    for (int i = tid; i < cnt; i += 512) {
        int v = tmp[cbase + i];            // L2-hot (second read)
        int ln = v >> 17;
        int p = atomicAdd(&cur[ln], 1);
        srt[gbase + p] = v & 0x1FFFF;      // random within 25KB window, L2-buffered
    }
}

// ---------- fp32 -> bf16 bulk convert (x -> xb, done once) ----------
__global__ __launch_bounds__(256) void cvt_kernel(const float* __restrict__ x,
                                                  ushort* __restrict__ xb) {
    const int n4 = N_NODES * D / 4;
    int i = blockIdx.x * 256 + threadIdx.x;
    const int stride = gridDim.x * 256;
    for (; i < n4; i += stride) {
        float4 v = ((const float4*)x)[i];
        ushort4 o;
        o.x = f2bf(v.x); o.y = f2bf(v.y); o.z = f2bf(v.z); o.w = f2bf(v.w);
        ((ushort4*)xb)[i] = o;
    }
}

// ---------- fused pull + linear: bf16 gather, node-pair, 8 loads in flight ----------
// Each wave owns node pair (2p, 2p+1). Lane layout: sub = lane&15 covers the
// 64-dim bf16 row as uint2 (8B = 4 bf16); g = lane>>4 selects edge slot.
// Both nodes' 16-edge batches are issued before any wait -> 8 gathers
// (+8 srt reads) outstanding per wave. Tail edges clamp to a valid index
// (duplicate row, L1-hit) and are masked via fmaf.
#define NBLK 2048
#define ACC4(P, M, AX, AY, AZ, AW)                        \
    {                                                     \
        float f0 = __uint_as_float((P).x << 16);          \
        float f1 = __uint_as_float((P).x & 0xffff0000u);  \
        float f2 = __uint_as_float((P).y << 16);          \
        float f3 = __uint_as_float((P).y & 0xffff0000u);  \
        AX = fmaf(f0, (M), AX); AY = fmaf(f1, (M), AY);   \
        AZ = fmaf(f2, (M), AZ); AW = fmaf(f3, (M), AW);   \
    }

__global__ __launch_bounds__(256) void fused_layer(const ushort* __restrict__ hb,
                                                   const int* __restrict__ offs,
                                                   const int* __restrict__ srt,
                                                   const float* __restrict__ W1,
                                                   const float* __restrict__ b1,
                                                   float* __restrict__ out,
                                                   ushort* __restrict__ outb) {
    __shared__ __align__(16) float rbA[4][64];
    __shared__ __align__(16) float rbB[4][64];
    const int tid  = threadIdx.x;
    const int lane = tid & 63;
    const int wid  = tid >> 6;
    const int g    = lane >> 4;      // edge slot group 0..3
    const int sub  = lane & 15;      // uint2 (4 bf16) within the row
    const int gw   = blockIdx.x * 4 + wid;
    const int GW   = NBLK * 4;
    const int goff = g << 2;

    float4 Wreg[16];
    const float4* wrow = (const float4*)(W1 + lane * D);
#pragma unroll
    for (int i = 0; i < 16; ++i) Wreg[i] = wrow[i];
    const float bj = b1[lane];

    for (int p = gw; p < (N_NODES >> 1); p += GW) {
        const int nA = p << 1;
        const int2 o2 = *(const int2*)(offs + nA);   // begA, endA(=begB)
        const int begA = o2.x;
        const int endA = o2.y;
        const int endB = offs[nA + 2];               // offs[N] sentinel = N_EDGES
        const int emA = (endA > begA) ? endA - 1 : begA;  // deg-0 safe (srt zero-padded)
        const int emB = (endB > endA) ? endB - 1 : endA;

        float aAx = 0.f, aAy = 0.f, aAz = 0.f, aAw = 0.f;
        float aBx = 0.f, aBy = 0.f, aBz = 0.f, aBw = 0.f;

        int ebA = begA, ebB = endA;
        while (ebA < endA || ebB < endB) {
            const int eA = ebA + goff;
            const int eB = ebB + goff;
            const int cA0 = min(eA,     emA), cA1 = min(eA + 1, emA);
            const int cA2 = min(eA + 2, emA), cA3 = min(eA + 3, emA);
            const int cB0 = min(eB,     emB), cB1 = min(eB + 1, emB);
            const int cB2 = min(eB + 2, emB), cB3 = min(eB + 3, emB);
            const int sA0 = __builtin_nontemporal_load(srt + cA0);
            const int sA1 = __builtin_nontemporal_load(srt + cA1);
            const int sA2 = __builtin_nontemporal_load(srt + cA2);
            const int sA3 = __builtin_nontemporal_load(srt + cA3);
            const int sB0 = __builtin_nontemporal_load(srt + cB0);
            const int sB1 = __builtin_nontemporal_load(srt + cB1);
            const int sB2 = __builtin_nontemporal_load(srt + cB2);
            const int sB3 = __builtin_nontemporal_load(srt + cB3);
            const uint2 vA0 = *((const uint2*)(hb + (ll)sA0 * D) + sub);
            const uint2 vA1 = *((const uint2*)(hb + (ll)sA1 * D) + sub);
            const uint2 vA2 = *((const uint2*)(hb + (ll)sA2 * D) + sub);
            const uint2 vA3 = *((const uint2*)(hb + (ll)sA3 * D) + sub);
            const uint2 vB0 = *((const uint2*)(hb + (ll)sB0 * D) + sub);
            const uint2 vB1 = *((const uint2*)(hb + (ll)sB1 * D) + sub);
            const uint2 vB2 = *((const uint2*)(hb + (ll)sB2 * D) + sub);
            const uint2 vB3 = *((const uint2*)(hb + (ll)sB3 * D) + sub);
            const float mA0 = (eA     < endA) ? 1.f : 0.f;
            const float mA1 = (eA + 1 < endA) ? 1.f : 0.f;
            const float mA2 = (eA + 2 < endA) ? 1.f : 0.f;
            const float mA3 = (eA + 3 < endA) ? 1.f : 0.f;
            const float mB0 = (eB     < endB) ? 1.f : 0.f;
            const float mB1 = (eB + 1 < endB) ? 1.f : 0.f;
            const float mB2 = (eB + 2 < endB) ? 1.f : 0.f;
            const float mB3 = (eB + 3 < endB) ? 1.f : 0.f;
            ACC4(vA0, mA0, aAx, aAy, aAz, aAw);
            ACC4(vA1, mA1, aAx, aAy, aAz, aAw);
            ACC4(vA2, mA2, aAx, aAy, aAz, aAw);
            ACC4(vA3, mA3, aAx, aAy, aAz, aAw);
            ACC4(vB0, mB0, aBx, aBy, aBz, aBw);
            ACC4(vB1, mB1, aBx, aBy, aBz, aBw);
            ACC4(vB2, mB2, aBx, aBy, aBz, aBw);
            ACC4(vB3, mB3, aBx, aBy, aBz, aBw);
            ebA += 16; ebB += 16;
        }

        // cross-group reduce: after xor16+xor32 every lane holds the full sum
        aAx += __shfl_xor(aAx, 16); aAy += __shfl_xor(aAy, 16);
        aAz += __shfl_xor(aAz, 16); aAw += __shfl_xor(aAw, 16);
        aBx += __shfl_xor(aBx, 16); aBy += __shfl_xor(aBy, 16);
        aBz += __shfl_xor(aBz, 16); aBw += __shfl_xor(aBw, 16);
        aAx += __shfl_xor(aAx, 32); aAy += __shfl_xor(aAy, 32);
        aAz += __shfl_xor(aAz, 32); aAw += __shfl_xor(aAw, 32);
        aBx += __shfl_xor(aBx, 32); aBy += __shfl_xor(aBy, 32);
        aBz += __shfl_xor(aBz, 32); aBw += __shfl_xor(aBw, 32);

        if (g == 0) {
            float4 t; t.x = aAx; t.y = aAy; t.z = aAz; t.w = aAw;
            *((float4*)rbA[wid] + sub) = t;     // wave-internal, in-order DS pipe
        }
        if (g == 1) {
            float4 t; t.x = aBx; t.y = aBy; t.z = aBz; t.w = aBw;
            *((float4*)rbB[wid] + sub) = t;
        }

        float oA = bj, oB = bj;
        const float4* ra = (const float4*)rbA[wid];
        const float4* rb = (const float4*)rbB[wid];
#pragma unroll
        for (int k4 = 0; k4 < 16; ++k4) {
            float4 rA = ra[k4];                  // broadcast read, conflict-free
            float4 rB = rb[k4];
            oA += rA.x * Wreg[k4].x + rA.y * Wreg[k4].y
                + rA.z * Wreg[k4].z + rA.w * Wreg[k4].w;
            oB += rB.x * Wreg[k4].x + rB.y * Wreg[k4].y
                + rB.z * Wreg[k4].z + rB.w * Wreg[k4].w;
        }
        __builtin_nontemporal_store(oA, out + (ll)nA * D + lane);
        __builtin_nontemporal_store(oB, out + (ll)(nA + 1) * D + lane);
        if (outb) {
            outb[(ll)nA * D + lane]       = f2bf(oA);
            outb[(ll)(nA + 1) * D + lane] = f2bf(oB);
        }
    }
}

extern "C" void kernel_launch(void* const* d_in, const int* in_sizes, int n_in,
                              void* d_out, int out_size, void* d_ws, size_t ws_size,
                              hipStream_t stream) {
    const float* x  = (const float*)d_in[0];   // [N, D]
    const int* edge = (const int*)d_in[1];     // [2, E]: src row then dst row
    const float* W1 = (const float*)d_in[2];   // [D, D]
    const float* b1 = (const float*)d_in[3];   // [D]

    const int* src = edge;
    const int* dst = edge + N_EDGES;

    float* out = (float*)d_out;                    // output 0: [N, D]
    float* hid = (float*)d_out + (ll)N_NODES * D;  // output 1: [N, D]

    // xb (bf16 copy of x) lives in the `out` region of d_out: it is only read
    // during layer 1 (which writes hid), and layer 2 overwrites every element.
    ushort* xb = (ushort*)d_out;

    // workspace layout (~23.5 MiB; 25.6 MB proven available)
    char* ws = (char*)d_ws;
    int* cursor   = (int*)ws;  ws += 1024;                                       // [196]
    int* bbase    = (int*)ws;  ws += 1024;                                       // [196]
    int* offs     = (int*)ws;  ws += ((size_t)(N_NODES + 1) * 4 + 255) & ~255ull;// [N+1]
    int* srt      = (int*)ws;  ws += ((size_t)(N_EDGES + 8) * 4 + 255) & ~255ull;// [E+8]
    ushort* hidb  = (ushort*)ws; ws += (size_t)N_NODES * D * 2;                  // [N,D] bf16
    int* tmp      = (int*)ws;                                                    // [196*CAP]

    // ---- build CSR via two-pass bucket sort (once; reused by both layers) ----
    init_kernel<<<1, 256, 0, stream>>>(cursor, srt, offs);
    bucketA_kernel<<<PA_BLOCKS, 256, 0, stream>>>(src, dst, cursor, tmp);
    scanSmall_kernel<<<1, 256, 0, stream>>>(cursor, bbase);
    bucketB_kernel<<<BUCKETS, 512, 0, stream>>>(cursor, bbase, tmp, srt, offs);

    // ---- bf16 copy of x ----
    cvt_kernel<<<2048, 256, 0, stream>>>(x, xb);

    // ---- layer 1: hid = segsum(x) @ W1^T + b1 (also emits bf16 hid copy) ----
    fused_layer<<<NBLK, 256, 0, stream>>>(xb, offs, srt, W1, b1, hid, hidb);
    // ---- layer 2: out = segsum(hid) @ W1^T + b1 ----
    fused_layer<<<NBLK, 256, 0, stream>>>(hidb, offs, srt, W1, b1, out, (ushort*)nullptr);
}

// Round 3
// 244.354 us; speedup vs baseline: 1.0175x; 1.0175x over previous
//
#include <hip/hip_runtime.h>

#define N_NODES 100000
#define N_EDGES 1250000
#define D 64

#define BSHIFT 9
#define BUCKETS 196          // ceil(100000 / 512)
#define CAP 8192             // srtTmp capacity per bucket (mean 6378, +22 sigma)
#define CHUNK 4096           // edges per bucketA block
#define PA_BLOCKS ((N_EDGES + CHUNK - 1) / CHUNK)   // 306
#define LCAP 64              // LDS list capacity per bucket per chunk (mean 21, max<64)

typedef long long ll;
typedef unsigned int uint;

// round-to-nearest-even fp32 -> bf16
__device__ __forceinline__ ushort f2bf(float f) {
    uint u = __float_as_uint(f);
    u += 0x7fffu + ((u >> 16) & 1u);
    return (ushort)(u >> 16);
}

// ---------- init: cursor[b] = b*CAP; zero-pad srt tail; offs[N] sentinel ----------
__global__ void init_kernel(int* __restrict__ cursor, int* __restrict__ srt,
                            int* __restrict__ offs) {
    int t = threadIdx.x;
    if (t < BUCKETS) cursor[t] = t * CAP;
    if (t < 8) srt[N_EDGES + t] = 0;
    if (t == 0) offs[N_NODES] = N_EDGES;
}

// ---------- pass A: bin edges into 196 coarse buckets ----------
// 512 threads; flush is two parallel phases: (1) 196 concurrent cursor atomics,
// (2) one coalesced 64-lane store per bucket (no serial per-thread copy loop).
__global__ __launch_bounds__(512) void bucketA_kernel(const int* __restrict__ src,
                                                      const int* __restrict__ dst,
                                                      int* __restrict__ cursor,
                                                      int* __restrict__ tmp) {
    __shared__ int lcnt[BUCKETS];
    __shared__ int gbs[BUCKETS];
    __shared__ int list[BUCKETS * LCAP];   // ~49 KB
    int tid = threadIdx.x;
    if (tid < BUCKETS) lcnt[tid] = 0;
    __syncthreads();

    int base = blockIdx.x * CHUNK;
    int nE = min(CHUNK, N_EDGES - base);
    for (int i = tid; i < nE; i += 512) {
        int e = base + i;
        int s = src[e], d = dst[e];
        int b = d >> BSHIFT;
        int p = atomicAdd(&lcnt[b], 1);            // LDS atomic, cheap
        list[b * LCAP + p] = s | ((d & 511) << 17); // src:17b, dstLow:9b
    }
    __syncthreads();

    if (tid < BUCKETS) gbs[tid] = atomicAdd(&cursor[tid], lcnt[tid]);  // parallel
    __syncthreads();

    int wv = tid >> 6, lane = tid & 63;
    for (int b = wv; b < BUCKETS; b += 8) {        // 8 waves, fire-and-forget stores
        int c = lcnt[b];
        if (lane < c) tmp[gbs[b] + lane] = list[b * LCAP + lane];
    }
}

// ---------- pass B: per-bucket local sort -> final srt + offs ----------
// Absorbs the global scan: every block recomputes the tiny 196-entry prefix sum.
__global__ __launch_bounds__(512) void bucketB_kernel(const int* __restrict__ cursor,
                                                      const int* __restrict__ tmp,
                                                      int* __restrict__ srt,
                                                      int* __restrict__ offs) {
    __shared__ int hist[512];
    __shared__ int s[512];
    __shared__ int cur[512];
    int b = blockIdx.x, tid = threadIdx.x;
    int cbase = b * CAP;
    int cnt = cursor[b] - cbase;

    // --- inline exclusive scan over 196 bucket counts (uses s[0..255]) ---
    if (tid < 256) s[tid] = (tid < BUCKETS) ? (cursor[tid] - tid * CAP) : 0;
    __syncthreads();
    for (int off = 1; off < 256; off <<= 1) {
        int v = (tid >= off && tid < 256) ? s[tid - off] : 0;
        __syncthreads();
        if (tid < 256) s[tid] += v;
        __syncthreads();
    }
    const int gbase = s[b] - cnt;       // exclusive prefix at own bucket
    __syncthreads();                    // before s[] is reused below

    hist[tid] = 0;
    __syncthreads();
    for (int i = tid; i < cnt; i += 512) {
        int ln = tmp[cbase + i] >> 17;
        atomicAdd(&hist[ln], 1);        // LDS atomic, avg 12.5/node
    }
    __syncthreads();

    // inclusive Hillis-Steele over 512 -> exclusive
    int x = hist[tid];
    s[tid] = x;
    __syncthreads();
    for (int off = 1; off < 512; off <<= 1) {
        int v = (tid >= off) ? s[tid - off] : 0;
        __syncthreads();
        s[tid] += v;
        __syncthreads();
    }
    int excl = s[tid] - x;
    cur[tid] = excl;

    int node0 = b << BSHIFT;
    int nloc = min(512, N_NODES - node0);
    if (tid < nloc) offs[node0 + tid] = gbase + excl;   // coalesced
    __syncthreads();

    for (int i = tid; i < cnt; i += 512) {
        int v = tmp[cbase + i];            // L2-hot (second read)
        int ln = v >> 17;
        int p = atomicAdd(&cur[ln], 1);
        srt[gbase + p] = v & 0x1FFFF;      // random within 25KB window, L2-buffered
    }
}

// ---------- fused pull + linear: 4 nodes/wave, 16 gathers in flight ----------
// Lane layout: sub = lane&15 covers one row (float4 for fp32, uint2=4bf16 for bf16);
// g = lane>>4 is the edge-slot quad. Per while-iteration each of the 4 nodes gets a
// 16-edge batch: 16 srt loads then 16 row-gathers issued back-to-back -> 16
// independent requests in flight per wave (the empirical lever: 4->8 was -20%).
// Next quad's offs are prefetched one iteration ahead. Tail slots clamp to a valid
// index (L1-hit duplicate) and are masked via fmaf.
#define NBLK 2048
#define NQ (N_NODES >> 2)

template<int BF16>
__device__ __forceinline__ float4 grow(const void* __restrict__ hbv, int s, int sub) {
    if (BF16) {
        const uint2 p = *((const uint2*)((const ushort*)hbv + (ll)s * D) + sub);
        float4 r;
        r.x = __uint_as_float(p.x << 16);
        r.y = __uint_as_float(p.x & 0xffff0000u);
        r.z = __uint_as_float(p.y << 16);
        r.w = __uint_as_float(p.y & 0xffff0000u);
        return r;
    } else {
        return *((const float4*)((const float*)hbv + (ll)s * D) + sub);
    }
}

#define NODE_IDX(L, EB, EM)                         \
    const int e##L = (EB) + goff;                   \
    const int c##L##0 = min(e##L,     (EM));        \
    const int c##L##1 = min(e##L + 1, (EM));        \
    const int c##L##2 = min(e##L + 2, (EM));        \
    const int c##L##3 = min(e##L + 3, (EM));        \
    const int s##L##0 = srt[c##L##0];               \
    const int s##L##1 = srt[c##L##1];               \
    const int s##L##2 = srt[c##L##2];               \
    const int s##L##3 = srt[c##L##3];

#define NODE_GATH(L)                                        \
    const float4 v##L##0 = grow<BF16>(hbv, s##L##0, sub);   \
    const float4 v##L##1 = grow<BF16>(hbv, s##L##1, sub);   \
    const float4 v##L##2 = grow<BF16>(hbv, s##L##2, sub);   \
    const float4 v##L##3 = grow<BF16>(hbv, s##L##3, sub);

#define ACCM(V, M, AX, AY, AZ, AW)                   \
    AX = fmaf((V).x, (M), AX); AY = fmaf((V).y, (M), AY); \
    AZ = fmaf((V).z, (M), AZ); AW = fmaf((V).w, (M), AW);

#define NODE_ACC(L, ENDV, AX, AY, AZ, AW)                     \
    {                                                         \
        const float m0 = (e##L     < (ENDV)) ? 1.f : 0.f;     \
        const float m1 = (e##L + 1 < (ENDV)) ? 1.f : 0.f;     \
        const float m2 = (e##L + 2 < (ENDV)) ? 1.f : 0.f;     \
        const float m3 = (e##L + 3 < (ENDV)) ? 1.f : 0.f;     \
        ACCM(v##L##0, m0, AX, AY, AZ, AW);                    \
        ACCM(v##L##1, m1, AX, AY, AZ, AW);                    \
        ACCM(v##L##2, m2, AX, AY, AZ, AW);                    \
        ACCM(v##L##3, m3, AX, AY, AZ, AW);                    \
    }

#define RED2(A) A += __shfl_xor(A, 16); A += __shfl_xor(A, 32);

template<int BF16>
__global__ __launch_bounds__(256) void fused_layer(const void* __restrict__ hbv,
                                                   const int* __restrict__ offs,
                                                   const int* __restrict__ srt,
                                                   const float* __restrict__ W1,
                                                   const float* __restrict__ b1,
                                                   float* __restrict__ out,
                                                   ushort* __restrict__ outb) {
    __shared__ __align__(16) float rb[4][4][64];   // [wave][node][col], 4 KB
    const int tid  = threadIdx.x;
    const int lane = tid & 63;
    const int wid  = tid >> 6;
    const int g    = lane >> 4;
    const int sub  = lane & 15;
    const int goff = g << 2;
    const int gw   = blockIdx.x * 4 + wid;
    const int GW   = NBLK * 4;

    float4 Wreg[16];
    const float4* wrow = (const float4*)(W1 + lane * D);
#pragma unroll
    for (int i = 0; i < 16; ++i) Wreg[i] = wrow[i];
    const float bj = b1[lane];

    if (gw >= NQ) return;
    int4 oc = *(const int4*)(offs + (gw << 2));
    int oce = offs[(gw << 2) + 4];

    for (int p = gw; p < NQ; p += GW) {
        // prefetch next quad's offs (used next iteration)
        const int pn = p + GW;
        const int pf = (pn < NQ) ? (pn << 2) : 0;
        const int4 on = *(const int4*)(offs + pf);
        const int one = offs[pf + 4];

        const int e0 = oc.x, e1 = oc.y, e2 = oc.z, e3 = oc.w, e4 = oce;
        const int emA = (e1 > e0) ? e1 - 1 : e0;   // deg-0 safe (srt zero-padded)
        const int emB = (e2 > e1) ? e2 - 1 : e1;
        const int emC = (e3 > e2) ? e3 - 1 : e2;
        const int emD = (e4 > e3) ? e4 - 1 : e3;

        float aAx = 0.f, aAy = 0.f, aAz = 0.f, aAw = 0.f;
        float aBx = 0.f, aBy = 0.f, aBz = 0.f, aBw = 0.f;
        float aCx = 0.f, aCy = 0.f, aCz = 0.f, aCw = 0.f;
        float aDx = 0.f, aDy = 0.f, aDz = 0.f, aDw = 0.f;

        int ebA = e0, ebB = e1, ebC = e2, ebD = e3;
        while (ebA < e1 || ebB < e2 || ebC < e3 || ebD < e4) {
            NODE_IDX(A, ebA, emA)
            NODE_IDX(B, ebB, emB)
            NODE_IDX(C, ebC, emC)
            NODE_IDX(D, ebD, emD)
            NODE_GATH(A)
            NODE_GATH(B)
            NODE_GATH(C)
            NODE_GATH(D)
            NODE_ACC(A, e1, aAx, aAy, aAz, aAw)
            NODE_ACC(B, e2, aBx, aBy, aBz, aBw)
            NODE_ACC(C, e3, aCx, aCy, aCz, aCw)
            NODE_ACC(D, e4, aDx, aDy, aDz, aDw)
            ebA += 16; ebB += 16; ebC += 16; ebD += 16;
        }

        // cross-group reduce: after xor16+xor32 every lane holds full sums
        RED2(aAx) RED2(aAy) RED2(aAz) RED2(aAw)
        RED2(aBx) RED2(aBy) RED2(aBz) RED2(aBw)
        RED2(aCx) RED2(aCy) RED2(aCz) RED2(aCw)
        RED2(aDx) RED2(aDy) RED2(aDz) RED2(aDw)

        if (g == 0) { float4 t; t.x = aAx; t.y = aAy; t.z = aAz; t.w = aAw;
                      *((float4*)rb[wid][0] + sub) = t; }
        if (g == 1) { float4 t; t.x = aBx; t.y = aBy; t.z = aBz; t.w = aBw;
                      *((float4*)rb[wid][1] + sub) = t; }
        if (g == 2) { float4 t; t.x = aCx; t.y = aCy; t.z = aCz; t.w = aCw;
                      *((float4*)rb[wid][2] + sub) = t; }
        if (g == 3) { float4 t; t.x = aDx; t.y = aDy; t.z = aDz; t.w = aDw;
                      *((float4*)rb[wid][3] + sub) = t; }
        // wave-internal LDS RAW: compiler inserts lgkmcnt wait; no barrier needed

        float oA = bj, oB = bj, oC = bj, oD = bj;
        const float4* rA = (const float4*)rb[wid][0];
        const float4* rB = (const float4*)rb[wid][1];
        const float4* rC = (const float4*)rb[wid][2];
        const float4* rD = (const float4*)rb[wid][3];
#pragma unroll
        for (int k4 = 0; k4 < 16; ++k4) {
            const float4 w = Wreg[k4];
            const float4 xA = rA[k4], xB = rB[k4], xC = rC[k4], xD = rD[k4];
            oA += xA.x * w.x + xA.y * w.y + xA.z * w.z + xA.w * w.w;
            oB += xB.x * w.x + xB.y * w.y + xB.z * w.z + xB.w * w.w;
            oC += xC.x * w.x + xC.y * w.y + xC.z * w.z + xC.w * w.w;
            oD += xD.x * w.x + xD.y * w.y + xD.z * w.z + xD.w * w.w;
        }
        const int nA = p << 2;
        __builtin_nontemporal_store(oA, out + (ll)nA * D + lane);
        __builtin_nontemporal_store(oB, out + (ll)(nA + 1) * D + lane);
        __builtin_nontemporal_store(oC, out + (ll)(nA + 2) * D + lane);
        __builtin_nontemporal_store(oD, out + (ll)(nA + 3) * D + lane);
        if (outb) {
            outb[(ll)nA * D + lane]       = f2bf(oA);   // plain store: keep L2-hot
            outb[(ll)(nA + 1) * D + lane] = f2bf(oB);
            outb[(ll)(nA + 2) * D + lane] = f2bf(oC);
            outb[(ll)(nA + 3) * D + lane] = f2bf(oD);
        }
        oc = on; oce = one;
    }
}

extern "C" void kernel_launch(void* const* d_in, const int* in_sizes, int n_in,
                              void* d_out, int out_size, void* d_ws, size_t ws_size,
                              hipStream_t stream) {
    const float* x  = (const float*)d_in[0];   // [N, D]
    const int* edge = (const int*)d_in[1];     // [2, E]: src row then dst row
    const float* W1 = (const float*)d_in[2];   // [D, D]
    const float* b1 = (const float*)d_in[3];   // [D]

    const int* src = edge;
    const int* dst = edge + N_EDGES;

    float* out = (float*)d_out;                    // output 0: [N, D]
    float* hid = (float*)d_out + (ll)N_NODES * D;  // output 1: [N, D]

    // workspace layout (~24.7 MiB; 25.6 MB proven available)
    char* ws = (char*)d_ws;
    int* cursor   = (int*)ws;  ws += 1024;                                       // [196]
    int* offs     = (int*)ws;  ws += ((size_t)(N_NODES + 1) * 4 + 255) & ~255ull;// [N+1]
    int* srt      = (int*)ws;  ws += ((size_t)(N_EDGES + 8) * 4 + 255) & ~255ull;// [E+8]
    ushort* hidb  = (ushort*)ws; ws += (size_t)N_NODES * D * 2;                  // [N,D] bf16
    int* tmp      = (int*)ws;                                                    // [196*CAP]

    // ---- build CSR via two-pass bucket sort (once; reused by both layers) ----
    init_kernel<<<1, 256, 0, stream>>>(cursor, srt, offs);
    bucketA_kernel<<<PA_BLOCKS, 512, 0, stream>>>(src, dst, cursor, tmp);
    bucketB_kernel<<<BUCKETS, 512, 0, stream>>>(cursor, tmp, srt, offs);

    // ---- layer 1: hid = segsum(x) @ W1^T + b1 (fp32 gather; emits bf16 hid) ----
    fused_layer<0><<<NBLK, 256, 0, stream>>>(x, offs, srt, W1, b1, hid, hidb);
    // ---- layer 2: out = segsum(hid) @ W1^T + b1 (bf16 gather) ----
    fused_layer<1><<<NBLK, 256, 0, stream>>>(hidb, offs, srt, W1, b1, out, (ushort*)nullptr);
}